// Round 14
// baseline (265.916 us; speedup 1.0000x reference)
//
#include <hip/hip_runtime.h>
#include <math.h>

#define NT 88200        // T
#define NB 8            // batch
#define TC 1378         // T // 64

static constexpr float IN_GAIN_F = 1.8197008586099834f; // 10^(5.2/20)

// ---- workspace layout (float offsets) ----
#define OFF_A0    3072         // L0 MFMA A-pack bf16 (2048 shorts)
#define OFF_A4    4096         // L4 MFMA A-pack bf16 (3072 shorts)
#define OFF_ABF   5632         // MFMA A-frag packs (v2: 16x16x32 layout), 3 layers x 12288 shorts
#define OFF_BANDS 24064        // [B][3][C][T] = 4233600
#define OFF_XRMS  4257664      // [24][TC] — sum of squares (zeroed by k_prep, atomically acc by k_firm)
#define OFF_ENV   4290736      // [24][TC]
#define OFF_WHL   4290736      // f16 shifted tap tables (4608 shorts) — overlaps ENV:
                               //   written by k_prep, read by k_firm, dead before k_scan writes ENV
// end 4323808 floats ~= 17.3 MB

typedef __attribute__((ext_vector_type(8))) short short8v;
typedef __attribute__((ext_vector_type(4))) short short4v;
typedef __attribute__((ext_vector_type(2))) unsigned int uint2v;
typedef __attribute__((ext_vector_type(4))) float float4v;
typedef __attribute__((ext_vector_type(8))) _Float16 half8v;

// hard-gelu: x * clamp(0.2837x + 0.5, 0, 1)  (hard-sigmoid of 1.702x).
// |err| vs exact gelu <= ~0.09; activations reach the output only via the
// 0.01-scaled residual conv (w4) -> contribution < 1e-3. 3 full-rate VALU, 0 TRANS.
__device__ __forceinline__ float gelu_h(float x) {
  float s = __builtin_amdgcn_fmed3f(fmaf(0.28366667f, x, 0.5f), 0.f, 1.f);
  return x * s;
}
__device__ __forceinline__ short f2bf(float x) {        // RNE
  unsigned int u = __float_as_uint(x);
  u += 0x7fffu + ((u >> 16) & 1u);
  return (short)(u >> 16);
}
__device__ __forceinline__ short f2fh(float x) {        // f32 -> f16 bits (RNE)
  union { _Float16 h; short s; } u;
  u.h = (_Float16)x;
  return u.s;
}
__device__ __forceinline__ half8v s2h(short8v s) {
  union { short8v s; half8v h; } u;
  u.s = s;
  return u.h;
}
// pack 2 f32 -> 2 bf16 (RNE) in one VALU op (no builtin on gfx950; T12 recipe)
__device__ __forceinline__ unsigned int cvt_pk_bf16(float lo, float hi) {
  unsigned int d;
  asm("v_cvt_pk_bf16_f32 %0, %1, %2" : "=v"(d) : "v"(lo), "v"(hi));
  return d;
}

// ---------------------------------------------------------------- prep
// task 0: composite FIR taps -> f16 shifted table (WHL) incl. zero edges;
// task 1: L0 A-pack; task 2: L4 A-pack; tasks 3..5: v2 16x16x32 A-packs w1..w3;
// task 6: zero XRMS accumulator.
__global__ __launch_bounds__(256) void k_prep(
    const float* __restrict__ irLL, const float* __restrict__ irLH,
    const float* __restrict__ irHL, const float* __restrict__ irHH,
    const float* __restrict__ w0, const float* __restrict__ w1,
    const float* __restrict__ w2, const float* __restrict__ w3,
    const float* __restrict__ w4, float* __restrict__ ws)
{
  int gid = blockIdx.x * 256 + threadIdx.x;
  int task = blockIdx.y;
  if (task == 0) {
    short* whl = (short*)(ws + OFF_WHL);
    if (gid < 3072) {                       // live taps
      int band = gid >> 10, j = gid & 1023;
      float v = 0.f;
      if (j < 1023) {
        if (band == 2) {                    // low: 512-tap, right-aligned
          v = (j >= 511) ? irLL[j - 511] : 0.f;
        } else {                            // high/mid: conv(irLH, irH?)
          const float* wb = (band == 0) ? irHH : irHL;
          int lo = j - 511; if (lo < 0) lo = 0;
          int hi = (j < 511) ? j : 511;
          float acc = 0.f;
          for (int i = lo; i <= hi; ++i) acc += irLH[i] * wb[j - i];
          v = acc;
        }
      }
      whl[band * 1152 + 64 + j] = f2fh(v);
    } else if (gid < 4608) {                // zero edges + band 3
      int z = gid - 3072;
      int entry;
      if (z < 384) {
        int band = z >> 7, r = z & 127;
        entry = band * 1152 + (r < 64 ? r : 1024 + r);
      } else {
        entry = 3 * 1152 + (z - 384);
      }
      whl[entry] = 0;
    }
  } else if (task == 1) {                   // L0 A-pack: m=oc(16/group), K=k*2+ic (6 live)
    if (gid >= 2048) return;
    int wq = gid >> 9;
    int lane = (gid >> 3) & 63;
    int j = gid & 7;
    int l16 = lane & 15, q = lane >> 4;
    int m = wq * 16 + l16;
    int K = q * 8 + j;
    float val = (K < 6) ? w0[(m * 2 + (K & 1)) * 3 + (K >> 1)] : 0.f;
    ((short*)(ws + OFF_A0))[gid] = f2bf(val);
  } else if (task == 2) {                   // L4 A-pack: rows m=ch (2 live of 16)
    if (gid >= 3072) return;
    int s = gid >> 9;
    int lane = (gid - s * 512) >> 3;
    int j = gid & 7;
    int m = lane & 15, q = lane >> 4;
    int K = s * 32 + q * 8 + j;
    int k = K >> 6, ic = K & 63;
    float val = (m < 2) ? w4[(m * 64 + ic) * 3 + k] : 0.f;
    ((short*)(ws + OFF_A4))[gid] = f2bf(val);
  } else if (task == 6) {                   // zero XRMS (24*TC = 33072 floats)
    for (int r = 0; r < 3; ++r) {
      int i = gid * 3 + r;
      if (i < 24 * TC) ws[OFF_XRMS + i] = 0.f;
    }
  } else {                                  // v2 A-pack layer l (w1..w3): 16x16x32 frags
    // entry = g*3072 + s*512 + lane*8 + j ; m = g*16 + (lane&15);
    // k = s*32 + ((lane>>4)&3)*8 + j ; tap = k/64 ; ic = k%64
    int l = task - 3;
    if (gid >= 12288) return;
    const float* wl = (l == 0) ? w1 : (l == 1) ? w2 : w3;
    int g = gid / 3072;
    int rem = gid - g * 3072;
    int s = rem / 512;
    int rem2 = rem - s * 512;
    int lane = rem2 >> 3;
    int j = gid & 7;
    int m = g * 16 + (lane & 15);
    int k = s * 32 + ((lane >> 4) & 3) * 8 + j;
    int tap = k >> 6, ic = k & 63;
    short* ap = (short*)(ws + OFF_ABF);
    ap[l * 12288 + gid] = f2bf(wl[(m * 64 + ic) * 3 + tap]);
  }
}

// ---------------------------------------------------------------- MFMA band FIR (+fused RMS partial)
// R16 form: single-chain f16 with 2-way accumulator ILP (even/odd s).
#define FT 320
__global__ __launch_bounds__(256) void k_firm(const float* __restrict__ audio,
                                              float* __restrict__ ws)
{
  __shared__ short xh[4][1360];
  __shared__ __align__(16) short wt[4608];
  __shared__ float ssum[3][5];
  int bc = blockIdx.x, tile = blockIdx.y;
  int t0b = tile * FT;
  int tid = threadIdx.x;
  if (tid < 15) ssum[tid / 5][tid % 5] = 0.f;
  const uint4* wsrc = (const uint4*)((const short*)(ws + OFF_WHL));
  uint4* wdst = (uint4*)wt;
  for (int i = tid; i < 576; i += 256) wdst[i] = wsrc[i];    // 4608 shorts = 576 uint4
  const float* x = audio + bc * NT;
  for (int i = tid; i < 1363; i += 256) {      // unique samples, convert once
    int g = t0b - 1022 + i;
    float v = (g >= 0 && g < NT) ? x[g] * IN_GAIN_F : 0.f;
    short h = f2fh(v);
#pragma unroll
    for (int c = 0; c < 4; ++c) {
      int idx = i - c;
      if (idx >= 0 && idx < 1360) xh[c][idx] = h;
    }
  }
  __syncthreads();

  int wave = tid >> 6, lane = tid & 63;
  int q = lane >> 4, l16 = lane & 15;
  int band = (l16 >= 10) ? 2 : (l16 >= 5 ? 1 : 0);
  if (l16 == 15) band = 3;
  int u = l16 - band * 5;                       // band3 -> u=0 (zero taps)
  const short* pAh = wt + band * 1152 + 64 + q * 8 - u * 16;
  int c = l16 & 3;
  int xoff = wave * 80 + q * 8 + ((l16 >> 2) << 2);
  const short* pBh = &xh[c][xoff];
  float4v a0 = {0.f, 0.f, 0.f, 0.f};
  float4v a1 = {0.f, 0.f, 0.f, 0.f};
#pragma unroll 2
  for (int s = 0; s < 34; s += 2) {
    half8v ah0 = *(const half8v*)(pAh + 32 * s);
    half8v ah1 = *(const half8v*)(pAh + 32 * (s + 1));
    short4v b00 = *(const short4v*)(pBh + 32 * s);
    short4v b01 = *(const short4v*)(pBh + 32 * s + 4);
    short4v b10 = *(const short4v*)(pBh + 32 * (s + 1));
    short4v b11 = *(const short4v*)(pBh + 32 * (s + 1) + 4);
    short8v bh0 = __builtin_shufflevector(b00, b01, 0, 1, 2, 3, 4, 5, 6, 7);
    short8v bh1 = __builtin_shufflevector(b10, b11, 0, 1, 2, 3, 4, 5, 6, 7);
    a0 = __builtin_amdgcn_mfma_f32_16x16x32_f16(ah0, s2h(bh0), a0, 0, 0, 0);
    a1 = __builtin_amdgcn_mfma_f32_16x16x32_f16(ah1, s2h(bh1), a1, 0, 0, 0);
  }
  float acc[4];
#pragma unroll
  for (int r = 0; r < 4; ++r) acc[r] = a0[r] + a1[r];

  int b = bc >> 1, ch = bc & 1;
  float* bands = ws + OFF_BANDS;
#pragma unroll
  for (int r = 0; r < 4; ++r) {
    int m = q * 4 + r;
    if (m < 15) {
      int bnd = (m >= 10) ? 2 : (m >= 5 ? 1 : 0);
      int uu = m - bnd * 5;
      int t = t0b + wave * 80 + uu * 16 + l16;
      if (t < NT) bands[((b * 3 + bnd) * 2 + ch) * NT + t] = acc[r];
    }
  }

  // ---- fused RMS partial: sum y^2 over each 16-sample group, accumulate
  float s2[4];
#pragma unroll
  for (int r = 0; r < 4; ++r) {
    int m = q * 4 + r;
    s2[r] = (m < 15) ? acc[r] * acc[r] : 0.f;
  }
#pragma unroll
  for (int mask = 1; mask < 16; mask <<= 1)
#pragma unroll
    for (int r = 0; r < 4; ++r)
      s2[r] += __shfl_xor(s2[r], mask, 16);
  if (l16 == 0) {
#pragma unroll
    for (int r = 0; r < 4; ++r) {
      int m = q * 4 + r;
      if (m < 15) {
        int bnd = (m >= 10) ? 2 : (m >= 5 ? 1 : 0);
        int uu = m - bnd * 5;
        int jloc = (wave * 80 + uu * 16) >> 6;
        atomicAdd(&ssum[bnd][jloc], s2[r]);
      }
    }
  }
  __syncthreads();
  if (tid < 15) {
    int bnd = tid / 5, jl = tid - bnd * 5;
    int jg = tile * 5 + jl;
    if (jg < TC) atomicAdd(&ws[OFF_XRMS + (b * 3 + bnd) * TC + jg], ssum[bnd][jl]);
  }
}

// ---------------------------------------------------------------- decaying-max scan (+sqrt)
// Work-efficient: 6 elems/thread in registers, one 256-wide Hillis-Steele over
// thread-partials (factor k^(6*off)), then register replay with exclusive carry.
__global__ __launch_bounds__(256) void k_scan(const float* __restrict__ rel_alphas,
                                              float* __restrict__ ws)
{
  __shared__ float pA[256], pB[256];
  int row = blockIdx.x;
  int tid = threadIdx.x;
  float kdec = 1.f - rel_alphas[row >> 3];   // reference's repeat() indexing
  const float* xr = ws + OFF_XRMS + row * TC;
  float v[6];
  int base = tid * 6;
#pragma unroll
  for (int s = 0; s < 6; ++s) {
    int j = base + s;
    v[s] = (j < TC) ? sqrtf(xr[j] * (0.5f / 64.f) + 1e-7f) : 0.f;  // pad 0: never wins
  }
  float r = v[0];
#pragma unroll
  for (int s = 1; s < 6; ++s) r = fmaxf(v[s], r * kdec);
  pA[tid] = r;
  __syncthreads();
  float k2 = kdec * kdec, k3 = k2 * kdec;
  float kp = k3 * k3;                        // k^6, then k^(6*off) via squaring
  float* in = pA; float* outp = pB;
  for (int off = 1; off < 256; off <<= 1) {
    float val = in[tid];
    if (tid >= off) val = fmaxf(val, in[tid - off] * kp);
    outp[tid] = val;
    kp *= kp;
    __syncthreads();
    float* tmp = in; in = outp; outp = tmp;
  }
  float* env = ws + OFF_ENV + row * TC;
  float rr;
  if (tid > 0) {
    float carry = in[tid - 1];               // inclusive up to position base-1
    rr = fmaxf(v[0], carry * kdec);
  } else {
    rr = v[0];
  }
  if (base < TC) env[base] = rr;
#pragma unroll
  for (int s = 1; s < 6; ++s) {
    rr = fmaxf(v[s], rr * kdec);
    if (base + s < TC) env[base + s] = rr;
  }
}

// ---------------------------------------------------------------- MFMA conv net (+fused gain)
// R24: B-reuse re-pairing. The 4 waves sharing a position-group read IDENTICAL
// B fragments (4x redundant LDS reads; B-reads are the dominant LDS traffic and
// LDS is at wire speed for b128 — swizzles can't help, only traffic cuts can).
// New wave mapping: wave = (g2 in {0,1}, p8 in {0..7}); each wave computes oc
// groups {g2, g2+2} x 2 sub-tiles. Same 24 MFMAs/wave; B-reads 24 -> 12/wave
// (LDS read traffic halves); A-reads 6 -> 12/wave, each reused 2x, overlapped.
// Addressing keeps the R18 allocator-clean shape (ternary base ptrs, immediate
// offsets). Accumulation order per output unchanged -> bit-identical numerics.
#define PITCH 72
#define SPAN 256
#define TILE 224

__device__ __forceinline__ void mfma_layer16(const short* in, short* outb,
    const short* __restrict__ apk, const float* __restrict__ bias,
    const int d, int t0, int g2, int p8, int lane)
{
  int l16 = lane & 15, l4 = (lane >> 4) & 3;
  const int ga = g2, gb = g2 + 2;
  const short* apA = apk + ga * 3072 + lane * 8;
  const short* apB = apk + gb * 3072 + lane * 8;
  float4 bva = *(const float4*)&bias[ga * 16 + l4 * 4];
  float4 bvb = *(const float4*)&bias[gb * 16 + l4 * 4];
  float4v accA[2], accB[2];
  const short* bp0[2];
  const short* bp1[2];
  const short* bp2[2];
#pragma unroll
  for (int st = 0; st < 2; ++st) {
    accA[st][0] = bva.x; accA[st][1] = bva.y; accA[st][2] = bva.z; accA[st][3] = bva.w;
    accB[st][0] = bvb.x; accB[st][1] = bvb.y; accB[st][2] = bvb.z; accB[st][3] = bvb.w;
    int pos = p8 * 32 + st * 16 + l16;
    int rm = pos - d; rm = rm < 0 ? 0 : rm;              // halo don't-care clamp
    int rp = pos + d; rp = rp > SPAN - 1 ? SPAN - 1 : rp;
    bp0[st] = in + rm * PITCH + l4 * 8;
    bp1[st] = in + pos * PITCH + l4 * 8;
    bp2[st] = in + rp * PITCH + l4 * 8;
  }
#pragma unroll
  for (int s = 0; s < 6; ++s) {
    short8v aA = *(const short8v*)(apA + s * 512);
    short8v aB = *(const short8v*)(apB + s * 512);
    const int tap = s >> 1;            // 0,0,1,1,2,2
    const int off = (s & 1) * 32;
#pragma unroll
    for (int st = 0; st < 2; ++st) {
      const short* base = (tap == 0) ? bp0[st] : (tap == 1) ? bp1[st] : bp2[st];
      short8v bf = *(const short8v*)(base + off);
      accA[st] = __builtin_amdgcn_mfma_f32_16x16x32_bf16(aA, bf, accA[st], 0, 0, 0);
      accB[st] = __builtin_amdgcn_mfma_f32_16x16x32_bf16(aB, bf, accB[st], 0, 0, 0);
    }
  }
#pragma unroll
  for (int st = 0; st < 2; ++st) {
    int pos = p8 * 32 + st * 16 + l16;
    int t = t0 - 16 + pos;
    bool z = (t < 0) | (t >= NT);
    uint2v ra, rb;
    ra[0] = cvt_pk_bf16(gelu_h(accA[st][0]), gelu_h(accA[st][1]));
    ra[1] = cvt_pk_bf16(gelu_h(accA[st][2]), gelu_h(accA[st][3]));
    rb[0] = cvt_pk_bf16(gelu_h(accB[st][0]), gelu_h(accB[st][1]));
    rb[1] = cvt_pk_bf16(gelu_h(accB[st][2]), gelu_h(accB[st][3]));
    ra[0] = z ? 0u : ra[0];
    ra[1] = z ? 0u : ra[1];
    rb[0] = z ? 0u : rb[0];
    rb[1] = z ? 0u : rb[1];
    *(uint2v*)(outb + pos * PITCH + ga * 16 + l4 * 4) = ra;
    *(uint2v*)(outb + pos * PITCH + gb * 16 + l4 * 4) = rb;
  }
}

__global__ __launch_bounds__(1024, 8) void k_convnet(
    const float* __restrict__ audio, const float* __restrict__ params,
    const float* __restrict__ kneep,
    const float* __restrict__ b0, const float* __restrict__ b1,
    const float* __restrict__ b2, const float* __restrict__ b3,
    const float* __restrict__ b4, const float* __restrict__ ws,
    float* __restrict__ out)
{
  __shared__ float cmb[2][SPAN];
  __shared__ __align__(16) char ubuf[SPAN * 8 * 2];  // bfL0
  __shared__ __align__(16) short actA[SPAN * PITCH];
  __shared__ __align__(16) short actB[SPAN * PITCH];
  short (*bfL0)[8] = (short(*)[8])ubuf;              // [SPAN][8] = 4096 B
  int tile = blockIdx.x, b = blockIdx.y;
  int t0 = tile * TILE;
  int tid = threadIdx.x;
  int wave = tid >> 6, lane = tid & 63;

  // ---- fused gain+combine+bfL0: threads (ch,pos) compute cc, write cmb AND
  // scatter their 3 bfL0 entries; threads 512.. zero the j=6,7 pad column.
  if (tid < 2 * SPAN) {
    int ch = tid >> 8;                 // SPAN == 256
    int pos = tid & (SPAN - 1);
    int t = t0 - 16 + pos;
    float cc = 0.f;
    if (t >= 0 && t < NT) {
      const float* env = ws + OFF_ENV;
      const float* bands = ws + OFF_BANDS;
      float knee = kneep[0];
      float halfk = 0.5f * knee;
      float inv2k = 1.f / (2.f * knee);
      const float scale = (float)(1377.0 / 88199.0);
      float pos_f = (float)t * scale;
      int i0 = (int)floorf(pos_f);
      i0 = i0 < 0 ? 0 : (i0 > TC - 2 ? TC - 2 : i0);
      float frac = pos_f - (float)i0;
      const int tacol[3] = {3, 2, 1};
      const int tbcol[3] = {6, 5, 4};
      const float asl[3] = {1.f, (float)(1.0 - 1.0 / 66.7), (float)(1.0 - 1.0 / 66.7)};
      const float bsl = (float)(1.0 - 1.0 / 4.17);
      const float og[3] = {10.3f, 5.7f, 10.3f};
#pragma unroll
      for (int band = 0; band < 3; ++band) {
        int row = b * 3 + band;
        float e = env[row * TC + i0] * (1.f - frac) + env[row * TC + i0 + 1] * frac;
        float edb = 6.0205999132796239f * __builtin_amdgcn_logf(e + 1e-7f);  // 20*log10
        float ta = params[b * 7 + tacol[band]];
        float tb = params[b * 7 + tbcol[band]];
        float d1 = edb - ta;
        float gk1 = asl[band] * (d1 + halfk) * (d1 + halfk) * inv2k;
        float ka = (fabsf(d1) <= halfk) ? gk1 : (d1 > halfk ? asl[band] * d1 : 0.f);
        float d2 = tb - edb;
        float gk2 = bsl * (d2 + halfk) * (d2 + halfk) * inv2k;
        float kb = (fabsf(d2) <= halfk) ? gk2 : (d2 > halfk ? bsl * d2 : 0.f);
        float gdb = -ka + kb + og[band];
        gdb = fminf(fmaxf(gdb, -80.f), 40.f);
        float g = __builtin_amdgcn_exp2f(gdb * 0.16609640474436812f);   // 10^(gdb/20)
        cc += bands[(row * 2 + ch) * NT + t] * g;
      }
    }
    cmb[ch][pos] = cc;
    // scatter bfL0[r][2k+ch] = bf16(cc) for r = pos+1-k, k=0..2 (each entry
    // written by exactly one thread; out-of-range r are the zero-pad edges)
    short hv = f2bf(cc);
#pragma unroll
    for (int k = 0; k < 3; ++k) {
      int r = pos + 1 - k;
      if (r >= 0 && r < SPAN) bfL0[r][2 * k + ch] = hv;
    }
    if (tid == 0) { bfL0[0][0] = 0; bfL0[0][1] = 0; }            // src pos -1
    if (tid == 1) { bfL0[SPAN - 1][4] = 0; bfL0[SPAN - 1][5] = 0; } // src pos SPAN
  } else {
    int z = tid - 2 * SPAN;            // 512 threads zero j=6,7 (SPAN*2 shorts)
    int r = z >> 1, j = 6 + (z & 1);
    bfL0[r][j] = 0;
  }
  __syncthreads();

  int quad = lane >> 4, l16 = lane & 15;

  // ---- L0 (MFMA 16x16x32): single K=32 step (6 live), B=bfL0
  {
    int wq = wave & 3, half = wave >> 2;               // half 0..3 covers 256 rows
    const short* ap0 = (const short*)(ws + OFF_A0);
    short8v a0 = *(const short8v*)&ap0[(wq * 64 + lane) * 8];
    float4 bv = *(const float4*)&b0[wq * 16 + quad * 4];
    float4v acc[4];
#pragma unroll
    for (int n = 0; n < 4; ++n) { acc[n][0] = bv.x; acc[n][1] = bv.y; acc[n][2] = bv.z; acc[n][3] = bv.w; }
    short8v zf = {0, 0, 0, 0, 0, 0, 0, 0};
#pragma unroll
    for (int n = 0; n < 4; ++n) {
      int row = (half * 4 + n) * 16 + l16;
      short8v bf = (quad == 0) ? *(const short8v*)&bfL0[row][0] : zf;
      acc[n] = __builtin_amdgcn_mfma_f32_16x16x32_bf16(a0, bf, acc[n], 0, 0, 0);
    }
    int ocb = wq * 16 + quad * 4;
#pragma unroll
    for (int n = 0; n < 4; ++n) {
      int p = (half * 4 + n) * 16 + l16;
      int t = t0 - 16 + p;
      bool z = (t < 0) | (t >= NT);
      uint2v r;
      r[0] = cvt_pk_bf16(gelu_h(acc[n][0]), gelu_h(acc[n][1]));
      r[1] = cvt_pk_bf16(gelu_h(acc[n][2]), gelu_h(acc[n][3]));
      r[0] = z ? 0u : r[0];
      r[1] = z ? 0u : r[1];
      *(uint2v*)&actA[p * PITCH + ocb] = r;
    }
  }
  __syncthreads();

  int g2 = wave & 1, p8 = wave >> 1;                   // R24 wave mapping
  const short* apk = (const short*)(ws + OFF_ABF);
  mfma_layer16(actA, actB, apk,          b1, 2, t0, g2, p8, lane);
  __syncthreads();
  mfma_layer16(actB, actA, apk + 12288,  b2, 4, t0, g2, p8, lane);
  __syncthreads();
  mfma_layer16(actA, actB, apk + 24576,  b3, 8, t0, g2, p8, lane);
  __syncthreads();

  // ---- L4 (MFMA 16x16x32): rows m=ch (2 live), waves 0..13 cover 224 outputs; + final mix
  if (wave < 14) {
    const short* ap4 = (const short*)(ws + OFF_A4);
    float4v acc = {0.f, 0.f, 0.f, 0.f};
    if (quad == 0) { acc[0] = b4[0]; acc[1] = b4[1]; }
#pragma unroll
    for (int s = 0; s < 6; ++s) {
      short8v a4 = *(const short8v*)&ap4[(s * 64 + lane) * 8];
      int kt = s >> 1;
      int ic0 = (s & 1) * 32 + quad * 8;
      int row = 16 + wave * 16 + l16 + kt - 1;
      short8v bf = *(const short8v*)&actB[row * PITCH + ic0];
      acc = __builtin_amdgcn_mfma_f32_16x16x32_bf16(a4, bf, acc, 0, 0, 0);
    }
    if (quad == 0) {
      int t = t0 + wave * 16 + l16;
      if (t < NT) {
        float amt = params[b * 7];
#pragma unroll
        for (int r = 0; r < 2; ++r) {
          float aud = audio[(b * 2 + r) * NT + t];
          out[(b * 2 + r) * NT + t] =
              (1.f - amt) * aud + amt * (cmb[r][16 + wave * 16 + l16] + acc[r]);
        }
      }
    }
  }
}

// ----------------------------------------------------------------
extern "C" void kernel_launch(void* const* d_in, const int* in_sizes, int n_in,
                              void* d_out, int out_size, void* d_ws, size_t ws_size,
                              hipStream_t stream)
{
  (void)in_sizes; (void)n_in; (void)out_size; (void)ws_size;
  const float* audio = (const float*)d_in[0];
  const float* params = (const float*)d_in[1];
  const float* rel   = (const float*)d_in[2];
  const float* knee  = (const float*)d_in[3];
  const float* irLL  = (const float*)d_in[4];
  const float* irLH  = (const float*)d_in[5];
  const float* irHL  = (const float*)d_in[6];
  const float* irHH  = (const float*)d_in[7];
  const float* w0 = (const float*)d_in[8];  const float* b0 = (const float*)d_in[9];
  const float* w1 = (const float*)d_in[10]; const float* b1 = (const float*)d_in[11];
  const float* w2 = (const float*)d_in[12]; const float* b2 = (const float*)d_in[13];
  const float* w3 = (const float*)d_in[14]; const float* b3 = (const float*)d_in[15];
  const float* w4 = (const float*)d_in[16]; const float* b4 = (const float*)d_in[17];
  float* out = (float*)d_out;
  float* ws  = (float*)d_ws;

  hipLaunchKernelGGL(k_prep, dim3(48, 7), dim3(256), 0, stream,
                     irLL, irLH, irHL, irHH, w0, w1, w2, w3, w4, ws);
  hipLaunchKernelGGL(k_firm, dim3(16, 276), dim3(256), 0, stream, audio, ws);
  hipLaunchKernelGGL(k_scan, dim3(24), dim3(256), 0, stream, rel, ws);
  hipLaunchKernelGGL(k_convnet, dim3(394, 8), dim3(1024), 0, stream,
                     audio, params, knee, b0, b1, b2, b3, b4, ws, out);
}

// Round 15
// 251.097 us; speedup vs baseline: 1.0590x; 1.0590x over previous
//
#include <hip/hip_runtime.h>
#include <math.h>

#define NT 88200        // T
#define NB 8            // batch
#define TC 1378         // T // 64

static constexpr float IN_GAIN_F = 1.8197008586099834f; // 10^(5.2/20)

// ---- workspace layout (float offsets) ----
#define OFF_A0    3072         // L0 MFMA A-pack bf16 (2048 shorts)
#define OFF_A4    4096         // L4 MFMA A-pack bf16 (3072 shorts)
#define OFF_ABF   5632         // MFMA A-frag packs (v2: 16x16x32 layout), 3 layers x 12288 shorts
#define OFF_BANDS 24064        // [B][3][C][T] = 4233600
#define OFF_XRMS  4257664      // [24][TC] — sum of squares (zeroed by k_prep, atomically acc by k_firm)
#define OFF_ENV   4290736      // [24][TC]
#define OFF_WHL   4290736      // f16 shifted tap tables (4608 shorts) — overlaps ENV:
                               //   written by k_prep, read by k_firm, dead before k_scan writes ENV
// end 4323808 floats ~= 17.3 MB

typedef __attribute__((ext_vector_type(8))) short short8v;
typedef __attribute__((ext_vector_type(4))) short short4v;
typedef __attribute__((ext_vector_type(2))) unsigned int uint2v;
typedef __attribute__((ext_vector_type(4))) float float4v;
typedef __attribute__((ext_vector_type(8))) _Float16 half8v;

// hard-gelu: x * clamp(0.2837x + 0.5, 0, 1)  (hard-sigmoid of 1.702x).
// |err| vs exact gelu <= ~0.09; activations reach the output only via the
// 0.01-scaled residual conv (w4) -> contribution < 1e-3. 3 full-rate VALU, 0 TRANS.
__device__ __forceinline__ float gelu_h(float x) {
  float s = __builtin_amdgcn_fmed3f(fmaf(0.28366667f, x, 0.5f), 0.f, 1.f);
  return x * s;
}
__device__ __forceinline__ short f2bf(float x) {        // RNE
  unsigned int u = __float_as_uint(x);
  u += 0x7fffu + ((u >> 16) & 1u);
  return (short)(u >> 16);
}
__device__ __forceinline__ short f2fh(float x) {        // f32 -> f16 bits (RNE)
  union { _Float16 h; short s; } u;
  u.h = (_Float16)x;
  return u.s;
}
__device__ __forceinline__ half8v s2h(short8v s) {
  union { short8v s; half8v h; } u;
  u.s = s;
  return u.h;
}
// pack 2 f32 -> 2 bf16 (RNE) in one VALU op (no builtin on gfx950; T12 recipe)
__device__ __forceinline__ unsigned int cvt_pk_bf16(float lo, float hi) {
  unsigned int d;
  asm("v_cvt_pk_bf16_f32 %0, %1, %2" : "=v"(d) : "v"(lo), "v"(hi));
  return d;
}

// ---------------------------------------------------------------- prep
// task 0: composite FIR taps -> f16 shifted table (WHL) incl. zero edges;
// task 1: L0 A-pack; task 2: L4 A-pack; tasks 3..5: v2 16x16x32 A-packs w1..w3;
// task 6: zero XRMS accumulator.
__global__ __launch_bounds__(256) void k_prep(
    const float* __restrict__ irLL, const float* __restrict__ irLH,
    const float* __restrict__ irHL, const float* __restrict__ irHH,
    const float* __restrict__ w0, const float* __restrict__ w1,
    const float* __restrict__ w2, const float* __restrict__ w3,
    const float* __restrict__ w4, float* __restrict__ ws)
{
  int gid = blockIdx.x * 256 + threadIdx.x;
  int task = blockIdx.y;
  if (task == 0) {
    short* whl = (short*)(ws + OFF_WHL);
    if (gid < 3072) {                       // live taps
      int band = gid >> 10, j = gid & 1023;
      float v = 0.f;
      if (j < 1023) {
        if (band == 2) {                    // low: 512-tap, right-aligned
          v = (j >= 511) ? irLL[j - 511] : 0.f;
        } else {                            // high/mid: conv(irLH, irH?)
          const float* wb = (band == 0) ? irHH : irHL;
          int lo = j - 511; if (lo < 0) lo = 0;
          int hi = (j < 511) ? j : 511;
          float acc = 0.f;
          for (int i = lo; i <= hi; ++i) acc += irLH[i] * wb[j - i];
          v = acc;
        }
      }
      whl[band * 1152 + 64 + j] = f2fh(v);
    } else if (gid < 4608) {                // zero edges + band 3
      int z = gid - 3072;
      int entry;
      if (z < 384) {
        int band = z >> 7, r = z & 127;
        entry = band * 1152 + (r < 64 ? r : 1024 + r);
      } else {
        entry = 3 * 1152 + (z - 384);
      }
      whl[entry] = 0;
    }
  } else if (task == 1) {                   // L0 A-pack: m=oc(16/group), K=k*2+ic (6 live)
    if (gid >= 2048) return;
    int wq = gid >> 9;
    int lane = (gid >> 3) & 63;
    int j = gid & 7;
    int l16 = lane & 15, q = lane >> 4;
    int m = wq * 16 + l16;
    int K = q * 8 + j;
    float val = (K < 6) ? w0[(m * 2 + (K & 1)) * 3 + (K >> 1)] : 0.f;
    ((short*)(ws + OFF_A0))[gid] = f2bf(val);
  } else if (task == 2) {                   // L4 A-pack: rows m=ch (2 live of 16)
    if (gid >= 3072) return;
    int s = gid >> 9;
    int lane = (gid - s * 512) >> 3;
    int j = gid & 7;
    int m = lane & 15, q = lane >> 4;
    int K = s * 32 + q * 8 + j;
    int k = K >> 6, ic = K & 63;
    float val = (m < 2) ? w4[(m * 64 + ic) * 3 + k] : 0.f;
    ((short*)(ws + OFF_A4))[gid] = f2bf(val);
  } else if (task == 6) {                   // zero XRMS (24*TC = 33072 floats)
    for (int r = 0; r < 3; ++r) {
      int i = gid * 3 + r;
      if (i < 24 * TC) ws[OFF_XRMS + i] = 0.f;
    }
  } else {                                  // v2 A-pack layer l (w1..w3): 16x16x32 frags
    // entry = g*3072 + s*512 + lane*8 + j ; m = g*16 + (lane&15);
    // k = s*32 + ((lane>>4)&3)*8 + j ; tap = k/64 ; ic = k%64
    int l = task - 3;
    if (gid >= 12288) return;
    const float* wl = (l == 0) ? w1 : (l == 1) ? w2 : w3;
    int g = gid / 3072;
    int rem = gid - g * 3072;
    int s = rem / 512;
    int rem2 = rem - s * 512;
    int lane = rem2 >> 3;
    int j = gid & 7;
    int m = g * 16 + (lane & 15);
    int k = s * 32 + ((lane >> 4) & 3) * 8 + j;
    int tap = k >> 6, ic = k & 63;
    short* ap = (short*)(ws + OFF_ABF);
    ap[l * 12288 + gid] = f2bf(wl[(m * 64 + ic) * 3 + tap]);
  }
}

// ---------------------------------------------------------------- MFMA band FIR (+fused RMS partial)
// R16 form: single-chain f16 with 2-way accumulator ILP (even/odd s).
#define FT 320
__global__ __launch_bounds__(256) void k_firm(const float* __restrict__ audio,
                                              float* __restrict__ ws)
{
  __shared__ short xh[4][1360];
  __shared__ __align__(16) short wt[4608];
  __shared__ float ssum[3][5];
  int bc = blockIdx.x, tile = blockIdx.y;
  int t0b = tile * FT;
  int tid = threadIdx.x;
  if (tid < 15) ssum[tid / 5][tid % 5] = 0.f;
  const uint4* wsrc = (const uint4*)((const short*)(ws + OFF_WHL));
  uint4* wdst = (uint4*)wt;
  for (int i = tid; i < 576; i += 256) wdst[i] = wsrc[i];    // 4608 shorts = 576 uint4
  const float* x = audio + bc * NT;
  for (int i = tid; i < 1363; i += 256) {      // unique samples, convert once
    int g = t0b - 1022 + i;
    float v = (g >= 0 && g < NT) ? x[g] * IN_GAIN_F : 0.f;
    short h = f2fh(v);
#pragma unroll
    for (int c = 0; c < 4; ++c) {
      int idx = i - c;
      if (idx >= 0 && idx < 1360) xh[c][idx] = h;
    }
  }
  __syncthreads();

  int wave = tid >> 6, lane = tid & 63;
  int q = lane >> 4, l16 = lane & 15;
  int band = (l16 >= 10) ? 2 : (l16 >= 5 ? 1 : 0);
  if (l16 == 15) band = 3;
  int u = l16 - band * 5;                       // band3 -> u=0 (zero taps)
  const short* pAh = wt + band * 1152 + 64 + q * 8 - u * 16;
  int c = l16 & 3;
  int xoff = wave * 80 + q * 8 + ((l16 >> 2) << 2);
  const short* pBh = &xh[c][xoff];
  float4v a0 = {0.f, 0.f, 0.f, 0.f};
  float4v a1 = {0.f, 0.f, 0.f, 0.f};
#pragma unroll 2
  for (int s = 0; s < 34; s += 2) {
    half8v ah0 = *(const half8v*)(pAh + 32 * s);
    half8v ah1 = *(const half8v*)(pAh + 32 * (s + 1));
    short4v b00 = *(const short4v*)(pBh + 32 * s);
    short4v b01 = *(const short4v*)(pBh + 32 * s + 4);
    short4v b10 = *(const short4v*)(pBh + 32 * (s + 1));
    short4v b11 = *(const short4v*)(pBh + 32 * (s + 1) + 4);
    short8v bh0 = __builtin_shufflevector(b00, b01, 0, 1, 2, 3, 4, 5, 6, 7);
    short8v bh1 = __builtin_shufflevector(b10, b11, 0, 1, 2, 3, 4, 5, 6, 7);
    a0 = __builtin_amdgcn_mfma_f32_16x16x32_f16(ah0, s2h(bh0), a0, 0, 0, 0);
    a1 = __builtin_amdgcn_mfma_f32_16x16x32_f16(ah1, s2h(bh1), a1, 0, 0, 0);
  }
  float acc[4];
#pragma unroll
  for (int r = 0; r < 4; ++r) acc[r] = a0[r] + a1[r];

  int b = bc >> 1, ch = bc & 1;
  float* bands = ws + OFF_BANDS;
#pragma unroll
  for (int r = 0; r < 4; ++r) {
    int m = q * 4 + r;
    if (m < 15) {
      int bnd = (m >= 10) ? 2 : (m >= 5 ? 1 : 0);
      int uu = m - bnd * 5;
      int t = t0b + wave * 80 + uu * 16 + l16;
      if (t < NT) bands[((b * 3 + bnd) * 2 + ch) * NT + t] = acc[r];
    }
  }

  // ---- fused RMS partial: sum y^2 over each 16-sample group, accumulate
  float s2[4];
#pragma unroll
  for (int r = 0; r < 4; ++r) {
    int m = q * 4 + r;
    s2[r] = (m < 15) ? acc[r] * acc[r] : 0.f;
  }
#pragma unroll
  for (int mask = 1; mask < 16; mask <<= 1)
#pragma unroll
    for (int r = 0; r < 4; ++r)
      s2[r] += __shfl_xor(s2[r], mask, 16);
  if (l16 == 0) {
#pragma unroll
    for (int r = 0; r < 4; ++r) {
      int m = q * 4 + r;
      if (m < 15) {
        int bnd = (m >= 10) ? 2 : (m >= 5 ? 1 : 0);
        int uu = m - bnd * 5;
        int jloc = (wave * 80 + uu * 16) >> 6;
        atomicAdd(&ssum[bnd][jloc], s2[r]);
      }
    }
  }
  __syncthreads();
  if (tid < 15) {
    int bnd = tid / 5, jl = tid - bnd * 5;
    int jg = tile * 5 + jl;
    if (jg < TC) atomicAdd(&ws[OFF_XRMS + (b * 3 + bnd) * TC + jg], ssum[bnd][jl]);
  }
}

// ---------------------------------------------------------------- decaying-max scan (+sqrt)
// Work-efficient: 6 elems/thread in registers, one 256-wide Hillis-Steele over
// thread-partials (factor k^(6*off)), then register replay with exclusive carry.
__global__ __launch_bounds__(256) void k_scan(const float* __restrict__ rel_alphas,
                                              float* __restrict__ ws)
{
  __shared__ float pA[256], pB[256];
  int row = blockIdx.x;
  int tid = threadIdx.x;
  float kdec = 1.f - rel_alphas[row >> 3];   // reference's repeat() indexing
  const float* xr = ws + OFF_XRMS + row * TC;
  float v[6];
  int base = tid * 6;
#pragma unroll
  for (int s = 0; s < 6; ++s) {
    int j = base + s;
    v[s] = (j < TC) ? sqrtf(xr[j] * (0.5f / 64.f) + 1e-7f) : 0.f;  // pad 0: never wins
  }
  float r = v[0];
#pragma unroll
  for (int s = 1; s < 6; ++s) r = fmaxf(v[s], r * kdec);
  pA[tid] = r;
  __syncthreads();
  float k2 = kdec * kdec, k3 = k2 * kdec;
  float kp = k3 * k3;                        // k^6, then k^(6*off) via squaring
  float* in = pA; float* outp = pB;
  for (int off = 1; off < 256; off <<= 1) {
    float val = in[tid];
    if (tid >= off) val = fmaxf(val, in[tid - off] * kp);
    outp[tid] = val;
    kp *= kp;
    __syncthreads();
    float* tmp = in; in = outp; outp = tmp;
  }
  float* env = ws + OFF_ENV + row * TC;
  float rr;
  if (tid > 0) {
    float carry = in[tid - 1];               // inclusive up to position base-1
    rr = fmaxf(v[0], carry * kdec);
  } else {
    rr = v[0];
  }
  if (base < TC) env[base] = rr;
#pragma unroll
  for (int s = 1; s < 6; ++s) {
    rr = fmaxf(v[s], rr * kdec);
    if (base + s < TC) env[base + s] = rr;
  }
}

// ---------------------------------------------------------------- MFMA conv net (+fused gain)
// R25 = final revert to the measured session best (R18/R23 form: k_convnet
// 102.5us, total 252.0us). Explored and rejected with counter evidence:
//  - LDS XOR swizzle (R19-21): conflicts 18M->3.9M but every register shape
//    carried ~45 B/thread scratch-class HBM writes, +12-16us net.
//  - B-reuse wave pairing (R24): conflicts ->11.6M, but doubled global A-reads
//    (undoing R17's +15%), +13us.
// Conclusion: LDS conflict cycles are hidden; critical path = A-load->MFMA
// chain + phase barriers. This configuration is the structure's optimum.
#define PITCH 72
#define SPAN 256
#define TILE 224

__device__ __forceinline__ void mfma_layer16(const short* in, short* outb,
    const short* __restrict__ apk, const float* __restrict__ bias,
    const int d, int t0, int g, int p, int lane)
{
  int l16 = lane & 15, l4 = (lane >> 4) & 3;
  const short* ap = apk + g * 3072 + lane * 8;
  float4 bv = *(const float4*)&bias[g * 16 + l4 * 4];
  float4v acc[4];
  const short* bp0[4];
  const short* bp1[4];
  const short* bp2[4];
#pragma unroll
  for (int st = 0; st < 4; ++st) {
    acc[st][0] = bv.x; acc[st][1] = bv.y; acc[st][2] = bv.z; acc[st][3] = bv.w;
    int pos = p * 64 + st * 16 + l16;
    int rm = pos - d; rm = rm < 0 ? 0 : rm;              // halo don't-care clamp
    int rp = pos + d; rp = rp > SPAN - 1 ? SPAN - 1 : rp;
    bp0[st] = in + rm * PITCH + l4 * 8;
    bp1[st] = in + pos * PITCH + l4 * 8;
    bp2[st] = in + rp * PITCH + l4 * 8;
  }
#pragma unroll
  for (int s = 0; s < 6; ++s) {
    short8v a = *(const short8v*)(ap + s * 512);
    const int tap = s >> 1;            // 0,0,1,1,2,2
    const int off = (s & 1) * 32;
#pragma unroll
    for (int st = 0; st < 4; ++st) {
      const short* base = (tap == 0) ? bp0[st] : (tap == 1) ? bp1[st] : bp2[st];
      short8v bf = *(const short8v*)(base + off);
      acc[st] = __builtin_amdgcn_mfma_f32_16x16x32_bf16(a, bf, acc[st], 0, 0, 0);
    }
  }
#pragma unroll
  for (int st = 0; st < 4; ++st) {
    int pos = p * 64 + st * 16 + l16;
    int t = t0 - 16 + pos;
    bool z = (t < 0) | (t >= NT);
    uint2v r;
    r[0] = cvt_pk_bf16(gelu_h(acc[st][0]), gelu_h(acc[st][1]));
    r[1] = cvt_pk_bf16(gelu_h(acc[st][2]), gelu_h(acc[st][3]));
    r[0] = z ? 0u : r[0];
    r[1] = z ? 0u : r[1];
    *(uint2v*)(outb + pos * PITCH + g * 16 + l4 * 4) = r;
  }
}

__global__ __launch_bounds__(1024, 8) void k_convnet(
    const float* __restrict__ audio, const float* __restrict__ params,
    const float* __restrict__ kneep,
    const float* __restrict__ b0, const float* __restrict__ b1,
    const float* __restrict__ b2, const float* __restrict__ b3,
    const float* __restrict__ b4, const float* __restrict__ ws,
    float* __restrict__ out)
{
  __shared__ float cmb[2][SPAN];
  __shared__ __align__(16) char ubuf[SPAN * 8 * 2];  // bfL0
  __shared__ __align__(16) short actA[SPAN * PITCH];
  __shared__ __align__(16) short actB[SPAN * PITCH];
  short (*bfL0)[8] = (short(*)[8])ubuf;              // [SPAN][8] = 4096 B
  int tile = blockIdx.x, b = blockIdx.y;
  int t0 = tile * TILE;
  int tid = threadIdx.x;
  int wave = tid >> 6, lane = tid & 63;

  // ---- fused gain+combine+bfL0: threads (ch,pos) compute cc, write cmb AND
  // scatter their 3 bfL0 entries; threads 512.. zero the j=6,7 pad column.
  if (tid < 2 * SPAN) {
    int ch = tid >> 8;                 // SPAN == 256
    int pos = tid & (SPAN - 1);
    int t = t0 - 16 + pos;
    float cc = 0.f;
    if (t >= 0 && t < NT) {
      const float* env = ws + OFF_ENV;
      const float* bands = ws + OFF_BANDS;
      float knee = kneep[0];
      float halfk = 0.5f * knee;
      float inv2k = 1.f / (2.f * knee);
      const float scale = (float)(1377.0 / 88199.0);
      float pos_f = (float)t * scale;
      int i0 = (int)floorf(pos_f);
      i0 = i0 < 0 ? 0 : (i0 > TC - 2 ? TC - 2 : i0);
      float frac = pos_f - (float)i0;
      const int tacol[3] = {3, 2, 1};
      const int tbcol[3] = {6, 5, 4};
      const float asl[3] = {1.f, (float)(1.0 - 1.0 / 66.7), (float)(1.0 - 1.0 / 66.7)};
      const float bsl = (float)(1.0 - 1.0 / 4.17);
      const float og[3] = {10.3f, 5.7f, 10.3f};
#pragma unroll
      for (int band = 0; band < 3; ++band) {
        int row = b * 3 + band;
        float e = env[row * TC + i0] * (1.f - frac) + env[row * TC + i0 + 1] * frac;
        float edb = 6.0205999132796239f * __builtin_amdgcn_logf(e + 1e-7f);  // 20*log10
        float ta = params[b * 7 + tacol[band]];
        float tb = params[b * 7 + tbcol[band]];
        float d1 = edb - ta;
        float gk1 = asl[band] * (d1 + halfk) * (d1 + halfk) * inv2k;
        float ka = (fabsf(d1) <= halfk) ? gk1 : (d1 > halfk ? asl[band] * d1 : 0.f);
        float d2 = tb - edb;
        float gk2 = bsl * (d2 + halfk) * (d2 + halfk) * inv2k;
        float kb = (fabsf(d2) <= halfk) ? gk2 : (d2 > halfk ? bsl * d2 : 0.f);
        float gdb = -ka + kb + og[band];
        gdb = fminf(fmaxf(gdb, -80.f), 40.f);
        float g = __builtin_amdgcn_exp2f(gdb * 0.16609640474436812f);   // 10^(gdb/20)
        cc += bands[(row * 2 + ch) * NT + t] * g;
      }
    }
    cmb[ch][pos] = cc;
    // scatter bfL0[r][2k+ch] = bf16(cc) for r = pos+1-k, k=0..2 (each entry
    // written by exactly one thread; out-of-range r are the zero-pad edges)
    short hv = f2bf(cc);
#pragma unroll
    for (int k = 0; k < 3; ++k) {
      int r = pos + 1 - k;
      if (r >= 0 && r < SPAN) bfL0[r][2 * k + ch] = hv;
    }
    if (tid == 0) { bfL0[0][0] = 0; bfL0[0][1] = 0; }            // src pos -1
    if (tid == 1) { bfL0[SPAN - 1][4] = 0; bfL0[SPAN - 1][5] = 0; } // src pos SPAN
  } else {
    int z = tid - 2 * SPAN;            // 512 threads zero j=6,7 (SPAN*2 shorts)
    int r = z >> 1, j = 6 + (z & 1);
    bfL0[r][j] = 0;
  }
  __syncthreads();

  int quad = lane >> 4, l16 = lane & 15;

  // ---- L0 (MFMA 16x16x32): single K=32 step (6 live), B=bfL0
  {
    int wq = wave & 3, half = wave >> 2;               // half 0..3 covers 256 rows
    const short* ap0 = (const short*)(ws + OFF_A0);
    short8v a0 = *(const short8v*)&ap0[(wq * 64 + lane) * 8];
    float4 bv = *(const float4*)&b0[wq * 16 + quad * 4];
    float4v acc[4];
#pragma unroll
    for (int n = 0; n < 4; ++n) { acc[n][0] = bv.x; acc[n][1] = bv.y; acc[n][2] = bv.z; acc[n][3] = bv.w; }
    short8v zf = {0, 0, 0, 0, 0, 0, 0, 0};
#pragma unroll
    for (int n = 0; n < 4; ++n) {
      int row = (half * 4 + n) * 16 + l16;
      short8v bf = (quad == 0) ? *(const short8v*)&bfL0[row][0] : zf;
      acc[n] = __builtin_amdgcn_mfma_f32_16x16x32_bf16(a0, bf, acc[n], 0, 0, 0);
    }
    int ocb = wq * 16 + quad * 4;
#pragma unroll
    for (int n = 0; n < 4; ++n) {
      int p = (half * 4 + n) * 16 + l16;
      int t = t0 - 16 + p;
      bool z = (t < 0) | (t >= NT);
      uint2v r;
      r[0] = cvt_pk_bf16(gelu_h(acc[n][0]), gelu_h(acc[n][1]));
      r[1] = cvt_pk_bf16(gelu_h(acc[n][2]), gelu_h(acc[n][3]));
      r[0] = z ? 0u : r[0];
      r[1] = z ? 0u : r[1];
      *(uint2v*)&actA[p * PITCH + ocb] = r;
    }
  }
  __syncthreads();

  int g16 = wave & 3, p16 = wave >> 2;                 // v2 wave mapping
  const short* apk = (const short*)(ws + OFF_ABF);
  mfma_layer16(actA, actB, apk,          b1, 2, t0, g16, p16, lane);
  __syncthreads();
  mfma_layer16(actB, actA, apk + 12288,  b2, 4, t0, g16, p16, lane);
  __syncthreads();
  mfma_layer16(actA, actB, apk + 24576,  b3, 8, t0, g16, p16, lane);
  __syncthreads();

  // ---- L4 (MFMA 16x16x32): rows m=ch (2 live), waves 0..13 cover 224 outputs; + final mix
  if (wave < 14) {
    const short* ap4 = (const short*)(ws + OFF_A4);
    float4v acc = {0.f, 0.f, 0.f, 0.f};
    if (quad == 0) { acc[0] = b4[0]; acc[1] = b4[1]; }
#pragma unroll
    for (int s = 0; s < 6; ++s) {
      short8v a4 = *(const short8v*)&ap4[(s * 64 + lane) * 8];
      int kt = s >> 1;
      int ic0 = (s & 1) * 32 + quad * 8;
      int row = 16 + wave * 16 + l16 + kt - 1;
      short8v bf = *(const short8v*)&actB[row * PITCH + ic0];
      acc = __builtin_amdgcn_mfma_f32_16x16x32_bf16(a4, bf, acc, 0, 0, 0);
    }
    if (quad == 0) {
      int t = t0 + wave * 16 + l16;
      if (t < NT) {
        float amt = params[b * 7];
#pragma unroll
        for (int r = 0; r < 2; ++r) {
          float aud = audio[(b * 2 + r) * NT + t];
          out[(b * 2 + r) * NT + t] =
              (1.f - amt) * aud + amt * (cmb[r][16 + wave * 16 + l16] + acc[r]);
        }
      }
    }
  }
}

// ----------------------------------------------------------------
extern "C" void kernel_launch(void* const* d_in, const int* in_sizes, int n_in,
                              void* d_out, int out_size, void* d_ws, size_t ws_size,
                              hipStream_t stream)
{
  (void)in_sizes; (void)n_in; (void)out_size; (void)ws_size;
  const float* audio = (const float*)d_in[0];
  const float* params = (const float*)d_in[1];
  const float* rel   = (const float*)d_in[2];
  const float* knee  = (const float*)d_in[3];
  const float* irLL  = (const float*)d_in[4];
  const float* irLH  = (const float*)d_in[5];
  const float* irHL  = (const float*)d_in[6];
  const float* irHH  = (const float*)d_in[7];
  const float* w0 = (const float*)d_in[8];  const float* b0 = (const float*)d_in[9];
  const float* w1 = (const float*)d_in[10]; const float* b1 = (const float*)d_in[11];
  const float* w2 = (const float*)d_in[12]; const float* b2 = (const float*)d_in[13];
  const float* w3 = (const float*)d_in[14]; const float* b3 = (const float*)d_in[15];
  const float* w4 = (const float*)d_in[16]; const float* b4 = (const float*)d_in[17];
  float* out = (float*)d_out;
  float* ws  = (float*)d_ws;

  hipLaunchKernelGGL(k_prep, dim3(48, 7), dim3(256), 0, stream,
                     irLL, irLH, irHL, irHH, w0, w1, w2, w3, w4, ws);
  hipLaunchKernelGGL(k_firm, dim3(16, 276), dim3(256), 0, stream, audio, ws);
  hipLaunchKernelGGL(k_scan, dim3(24), dim3(256), 0, stream, rel, ws);
  hipLaunchKernelGGL(k_convnet, dim3(394, 8), dim3(1024), 0, stream,
                     audio, params, knee, b0, b1, b2, b3, b4, ws, out);
}